// Round 7
// baseline (228.832 us; speedup 1.0000x reference)
//
#include <hip/hip_runtime.h>
#include <hip/hip_bf16.h>

typedef __attribute__((ext_vector_type(8))) short bf16x8;
typedef __attribute__((ext_vector_type(4))) float f32x4;

#define MFMA_BF16 __builtin_amdgcn_mfma_f32_16x16x32_bf16

#define GLDS16(gp, lp)                                                        \
  __builtin_amdgcn_global_load_lds(                                           \
      (const __attribute__((address_space(1))) void*)(gp),                    \
      (__attribute__((address_space(3))) void*)(lp), 16, 0, 0)

__device__ __forceinline__ unsigned pk2(float a, float b) {
  __hip_bfloat162 t = __float22bfloat162_rn(make_float2(a, b));
  return *reinterpret_cast<unsigned*>(&t);
}
__device__ __forceinline__ unsigned short f2bf_hw(float f) {
  __hip_bfloat16 h = __float2bfloat16(f);
  return *reinterpret_cast<unsigned short*>(&h);
}
__device__ __forceinline__ float sigm(float x) {
  return __builtin_amdgcn_rcpf(1.f + __expf(-x));
}
__device__ __forceinline__ float tanh_f(float x) {
  return 1.f - 2.f * __builtin_amdgcn_rcpf(1.f + __expf(2.f * x));
}

// ---------------------------------------------------------------------------
// k0: one-time weight conversion to frag-major bf16 tables in d_ws.
// ---------------------------------------------------------------------------
__global__ void k0_conv(const float* __restrict__ W0, const float* __restrict__ Wfw,
                        const float* __restrict__ Wbw, unsigned short* __restrict__ wfrag,
                        unsigned short* __restrict__ wlstm) {
  int gid = blockIdx.x * 256 + threadIdx.x;
  if (gid < 4096) {
    int f = gid >> 6, l = gid & 63;
    int k0 = (f >> 2) * 32 + ((l >> 4) << 3);
    int n = (f & 3) * 16 + (l & 15);
    bf16x8 v;
#pragma unroll
    for (int j = 0; j < 8; ++j) v[j] = (short)f2bf_hw(W0[(k0 + j) * 64 + n]);
    *(bf16x8*)(wfrag + gid * 8) = v;
  } else if (gid < 12288) {
    int g2 = gid - 4096;
    const float* W = (g2 < 4096) ? Wfw : Wbw;
    int f = (g2 & 4095) >> 6, l = g2 & 63;
    int wv = f >> 4, gate = (f >> 2) & 3, kf = f & 3;
    int col = gate * 64 + wv * 16 + (l & 15);
    int kr = kf * 32 + ((l >> 4) << 3);
    bf16x8 v;
#pragma unroll
    for (int j = 0; j < 8; ++j) v[j] = (short)f2bf_hw(W[(kr + j) * 256 + col]);
    *(bf16x8*)(wlstm + g2 * 8) = v;
  }
}

// ---------------------------------------------------------------------------
// K1: x = relu(layernorm(obs @ W0 + b0)) -> bf16 [131072, 64]
// UNCHANGED from R6 (passing). Duplicated launch this round for attribution.
// ---------------------------------------------------------------------------
__global__ __launch_bounds__(256, 2) void k_dense_ln(
    const float* __restrict__ obs, const unsigned short* __restrict__ wfrag,
    const float* __restrict__ b0, const float* __restrict__ gam,
    const float* __restrict__ bet, unsigned short* __restrict__ xout) {
  __shared__ __align__(16) char lds[65536];
  const int tid = threadIdx.x, w = tid >> 6, l = tid & 63;
  const int g = l >> 4, c = l & 15;
  const long blk64 = (long)blockIdx.x * 64;
  const long rb = blk64 + w * 16;

  float b0v[4], gv[4], bv[4];
#pragma unroll
  for (int nt = 0; nt < 4; ++nt) {
    int col = nt * 16 + c;
    b0v[nt] = b0[col]; gv[nt] = gam[col]; bv[nt] = bet[col];
  }
  const unsigned short* wfl = wfrag + l * 8;

  const int sr0 = w * 16 + (l >> 5);
  const int su = l & 31;
  const char* gB = (const char*)obs + blk64 * 2048;

  asm volatile("s_waitcnt vmcnt(0)" ::: "memory");

#define K1_STAGE(q)                                                           \
  {                                                                           \
    _Pragma("unroll") for (int i = 0; i < 8; ++i) {                           \
      int r_ = sr0 + 2 * i;                                                   \
      int chk_ = su ^ (r_ & 7);                                               \
      const char* gp_ = gB + (long)r_ * 2048 + (q) * 512 + chk_ * 16;         \
      char* lp_ = lds + ((q) & 1) * 32768 + (w * 512 + i * 64) * 16;          \
      GLDS16(gp_, lp_);                                                       \
    }                                                                         \
  }

  K1_STAGE(0);
  K1_STAGE(1);

  f32x4 acc[4];
#pragma unroll
  for (int nt = 0; nt < 4; ++nt) acc[nt] = (f32x4){0.f, 0.f, 0.f, 0.f};

#pragma unroll
  for (int q = 0; q < 4; ++q) {
    if (q < 3) asm volatile("s_waitcnt vmcnt(8)" ::: "memory");
    else       asm volatile("s_waitcnt vmcnt(0)" ::: "memory");
    __builtin_amdgcn_s_barrier();
    __builtin_amdgcn_sched_barrier(0);

    const char* bufb = lds + (q & 1) * 32768 + (w * 16 + c) * 512;
#pragma unroll
    for (int kf2 = 0; kf2 < 4; ++kf2) {
      bf16x8 B0 = *(const bf16x8*)(wfl + ((q * 4 + kf2) * 4 + 0) * 512);
      bf16x8 B1 = *(const bf16x8*)(wfl + ((q * 4 + kf2) * 4 + 1) * 512);
      bf16x8 B2 = *(const bf16x8*)(wfl + ((q * 4 + kf2) * 4 + 2) * 512);
      bf16x8 B3 = *(const bf16x8*)(wfl + ((q * 4 + kf2) * 4 + 3) * 512);
      int v0 = kf2 * 8 + g * 2;
      float4 f0 = *(const float4*)(bufb + ((v0 + 0) ^ (c & 7)) * 16);
      float4 f1 = *(const float4*)(bufb + ((v0 + 1) ^ (c & 7)) * 16);
      union { bf16x8 v; unsigned u[4]; } af;
      af.u[0] = pk2(f0.x, f0.y); af.u[1] = pk2(f0.z, f0.w);
      af.u[2] = pk2(f1.x, f1.y); af.u[3] = pk2(f1.z, f1.w);
      acc[0] = MFMA_BF16(af.v, B0, acc[0], 0, 0, 0);
      acc[1] = MFMA_BF16(af.v, B1, acc[1], 0, 0, 0);
      acc[2] = MFMA_BF16(af.v, B2, acc[2], 0, 0, 0);
      acc[3] = MFMA_BF16(af.v, B3, acc[3], 0, 0, 0);
    }
    if (q < 2) {
      __builtin_amdgcn_s_barrier();
      __builtin_amdgcn_sched_barrier(0);
      K1_STAGE(q + 2);
    }
  }

  float vv[4][4], s1[4], s2[4];
#pragma unroll
  for (int r = 0; r < 4; ++r) { s1[r] = 0.f; s2[r] = 0.f; }
#pragma unroll
  for (int nt = 0; nt < 4; ++nt)
#pragma unroll
    for (int r = 0; r < 4; ++r) {
      float val = acc[nt][r] + b0v[nt];
      vv[nt][r] = val; s1[r] += val; s2[r] += val * val;
    }
#pragma unroll
  for (int r = 0; r < 4; ++r) {
#pragma unroll
    for (int m = 1; m <= 8; m <<= 1) {
      s1[r] += __shfl_xor(s1[r], m);
      s2[r] += __shfl_xor(s2[r], m);
    }
  }
  unsigned short* xw = (unsigned short*)lds + w * 1024;
#pragma unroll
  for (int r = 0; r < 4; ++r) {
    float mu = s1[r] * 0.015625f;
    float var = s2[r] * 0.015625f - mu * mu;
    float inv = rsqrtf(var + 1e-12f);
    int row = g * 4 + r;
#pragma unroll
    for (int nt = 0; nt < 4; ++nt) {
      float xn = (vv[nt][r] - mu) * inv * gv[nt] + bv[nt];
      xw[(row * 64 + nt * 16 + c) ^ (g << 3)] = f2bf_hw(fmaxf(xn, 0.f));
    }
  }
#pragma unroll
  for (int m2 = 0; m2 < 2; ++m2) {
    int m = m2 * 64 + l;
    int row = m >> 3, u8 = m & 7;
    bf16x8 v = *(const bf16x8*)(xw + ((row * 64 + u8 * 8) ^ ((row >> 2) << 3)));
    *(bf16x8*)(xout + (rb + row) * 64 + u8 * 8) = v;
  }
}

// ---------------------------------------------------------------------------
// K2: bidirectional LSTM + fused projection. UNCHANGED from R6 (passing).
// Launched 3x this round for attribution.
// ---------------------------------------------------------------------------
__global__ __launch_bounds__(256, 2) void k_lstm(
    const unsigned short* __restrict__ x, const unsigned short* __restrict__ wlstm,
    const float* __restrict__ bfw, const float* __restrict__ bbw,
    const float* __restrict__ Wc, const float* __restrict__ bc,
    float* __restrict__ out) {
  __shared__ __align__(16) char xl[65536];
  __shared__ unsigned short hl[2 * 1024];
  const int tid = threadIdx.x, w = tid >> 6, l = tid & 63;
  const int g = l >> 4, c = l & 15;
  const int dir = blockIdx.x >> 8;
  const int sq = (blockIdx.x & 255) * 16;
  const float* bias = dir ? bbw : bfw;

  bf16x8 Bf[4][4];
  const unsigned short* wl = wlstm + ((long)dir * 4096 + w * 16 * 64) * 8;
#pragma unroll
  for (int gate = 0; gate < 4; ++gate)
#pragma unroll
    for (int kf = 0; kf < 4; ++kf)
      Bf[gate][kf] = *(const bf16x8*)(wl + ((gate * 4 + kf) * 64 + l) * 8);
  float bz[4];
#pragma unroll
  for (int gate = 0; gate < 4; ++gate) bz[gate] = bias[gate * 64 + w * 16 + c];

  bf16x8 Pc[2];
#pragma unroll
  for (int kf = 0; kf < 2; ++kf)
#pragma unroll
    for (int j = 0; j < 8; ++j) Pc[kf][j] = 0;
  float bcv = 0.f;
  if (w == 0 && c < 8) {
#pragma unroll
    for (int kf = 0; kf < 2; ++kf)
#pragma unroll
      for (int j = 0; j < 8; ++j)
        Pc[kf][j] = (short)f2bf_hw(Wc[(kf * 32 + g * 8 + j) * 8 + c]);
    bcv = bc[c];
  }

  asm volatile("s_waitcnt vmcnt(0)" ::: "memory");

  const int ss = l >> 3, sc = l & 7;
#pragma unroll
  for (int j = 0; j < 8; ++j) {
    int tt = w * 8 + j;
    int te = dir ? 31 - tt : tt;
#pragma unroll
    for (int p = 0; p < 2; ++p) {
      int s = p * 8 + ss;
      const char* gp = (const char*)x +
          ((long)(sq + s) * 32 + te) * 128 + (long)(sc ^ (s & 7)) * 16;
      char* lp = xl + tt * 2048 + p * 1024;
      GLDS16(gp, lp);
    }
  }

  for (int i = tid; i < 1024; i += 256) ((unsigned*)hl)[i] = 0u;
  float cs[4] = {0.f, 0.f, 0.f, 0.f};

  if (w == 0) asm volatile("s_waitcnt vmcnt(14)" ::: "memory");
  asm volatile("s_waitcnt lgkmcnt(0)" ::: "memory");
  __builtin_amdgcn_s_barrier();
  __builtin_amdgcn_sched_barrier(0);

  const int hq = w >> 1;
  const int hgp = ((w & 1) * 2 + (c >> 3)) * 16;
  const int hlo = c & 7;

  int p = 0;
#pragma unroll
  for (int t = 0; t < 32; ++t) {
    const int te = dir ? 31 - t : t;
    const char* xt = xl + t * 2048 + c * 128;
    bf16x8 Ax0 = *(const bf16x8*)(xt + (long)((g) ^ (c & 7)) * 16);
    bf16x8 Ax1 = *(const bf16x8*)(xt + (long)((4 + g) ^ (c & 7)) * 16);
    bf16x8 Ah0 = *(const bf16x8*)((const char*)hl + p * 2048 + l * 16);
    bf16x8 Ah1 = *(const bf16x8*)((const char*)hl + p * 2048 + 1024 + l * 16);

    f32x4 acc[4];
#pragma unroll
    for (int gate = 0; gate < 4; ++gate)
      acc[gate] = (f32x4){bz[gate], bz[gate], bz[gate], bz[gate]};
#pragma unroll
    for (int gate = 0; gate < 4; ++gate) {
      acc[gate] = MFMA_BF16(Ax0, Bf[gate][0], acc[gate], 0, 0, 0);
      acc[gate] = MFMA_BF16(Ax1, Bf[gate][1], acc[gate], 0, 0, 0);
      acc[gate] = MFMA_BF16(Ah0, Bf[gate][2], acc[gate], 0, 0, 0);
      acc[gate] = MFMA_BF16(Ah1, Bf[gate][3], acc[gate], 0, 0, 0);
    }

    const int wb = (p ^ 1) * 1024;
#pragma unroll
    for (int r = 0; r < 4; ++r) {
      float si = sigm(acc[0][r]);
      float tj = tanh_f(acc[1][r]);
      float sf = sigm(acc[2][r] + 1.f);
      float so = sigm(acc[3][r]);
      cs[r] = cs[r] * sf + si * tj;
      hl[wb + (hq * 64 + hgp + 4 * g + r) * 8 + hlo] = f2bf_hw(tanh_f(cs[r]) * so);
    }

    if (t + 1 < 32) {
      if (w == ((t + 1) >> 3))
        asm volatile("s_waitcnt vmcnt(%0)" :: "i"(14 - 2 * ((t + 1) & 7)) : "memory");
    }
    asm volatile("s_waitcnt lgkmcnt(0)" ::: "memory");
    __builtin_amdgcn_s_barrier();
    __builtin_amdgcn_sched_barrier(0);

    if (w == 0 && t >= 1) {
      f32x4 pa = (f32x4){0.f, 0.f, 0.f, 0.f};
      pa = MFMA_BF16(Ah0, Pc[0], pa, 0, 0, 0);
      pa = MFMA_BF16(Ah1, Pc[1], pa, 0, 0, 0);
      if (c < 8) {
        int tp = dir ? 32 - t : t - 1;
#pragma unroll
        for (int r = 0; r < 4; ++r) {
          long orow = (long)dir * 4096 + sq + 4 * g + r;
          out[(orow * 32 + tp) * 8 + c] = tanh_f(pa[r] + bcv);
        }
      }
    }
    p ^= 1;
  }

  if (w == 0) {
    bf16x8 Ph0 = *(const bf16x8*)((const char*)hl + p * 2048 + l * 16);
    bf16x8 Ph1 = *(const bf16x8*)((const char*)hl + p * 2048 + 1024 + l * 16);
    f32x4 pa = (f32x4){0.f, 0.f, 0.f, 0.f};
    pa = MFMA_BF16(Ph0, Pc[0], pa, 0, 0, 0);
    pa = MFMA_BF16(Ph1, Pc[1], pa, 0, 0, 0);
    if (c < 8) {
      int tp = dir ? 0 : 31;
#pragma unroll
      for (int r = 0; r < 4; ++r) {
        long orow = (long)dir * 4096 + sq + 4 * g + r;
        out[(orow * 32 + tp) * 8 + c] = tanh_f(pa[r] + bcv);
      }
    }
  }
}

extern "C" void kernel_launch(void* const* d_in, const int* in_sizes, int n_in,
                              void* d_out, int out_size, void* d_ws, size_t ws_size,
                              hipStream_t stream) {
  const float* obs = (const float*)d_in[0];
  const float* W0  = (const float*)d_in[1];
  const float* b0  = (const float*)d_in[2];
  const float* gam = (const float*)d_in[3];
  const float* bet = (const float*)d_in[4];
  const float* Wfw = (const float*)d_in[5];
  const float* bfw = (const float*)d_in[6];
  const float* Wbw = (const float*)d_in[7];
  const float* bbw = (const float*)d_in[8];
  const float* Wc  = (const float*)d_in[9];
  const float* bc  = (const float*)d_in[10];
  float* out = (float*)d_out;

  unsigned short* wfrag = (unsigned short*)d_ws;       // 64 KB
  unsigned short* wlstm = wfrag + 4096 * 8;            // 128 KB
  unsigned short* xbf   = wlstm + 8192 * 8;            // 16.78 MB

  // ATTRIBUTION ROUND: K1 x2, K2 x3 (all idempotent; deterministic).
  // total' - total = K1 + 2*K2.
  k0_conv<<<48, 256, 0, stream>>>(W0, Wfw, Wbw, wfrag, wlstm);
  k_dense_ln<<<2048, 256, 0, stream>>>(obs, wfrag, b0, gam, bet, xbf);
  k_dense_ln<<<2048, 256, 0, stream>>>(obs, wfrag, b0, gam, bet, xbf);
  k_lstm<<<512, 256, 0, stream>>>(xbf, wlstm, bfw, bbw, Wc, bc, out);
  k_lstm<<<512, 256, 0, stream>>>(xbf, wlstm, bfw, bbw, Wc, bc, out);
  k_lstm<<<512, 256, 0, stream>>>(xbf, wlstm, bfw, bbw, Wc, bc, out);
}

// Round 8
// 102.308 us; speedup vs baseline: 2.2367x; 2.2367x over previous
//
#include <hip/hip_runtime.h>
#include <hip/hip_bf16.h>

typedef __attribute__((ext_vector_type(8))) short bf16x8;
typedef __attribute__((ext_vector_type(4))) float f32x4;

#define MFMA_BF16 __builtin_amdgcn_mfma_f32_16x16x32_bf16

#define GLDS16(gp, lp)                                                        \
  __builtin_amdgcn_global_load_lds(                                           \
      (const __attribute__((address_space(1))) void*)(gp),                    \
      (__attribute__((address_space(3))) void*)(lp), 16, 0, 0)

__device__ __forceinline__ unsigned pk2(float a, float b) {
  __hip_bfloat162 t = __float22bfloat162_rn(make_float2(a, b));
  return *reinterpret_cast<unsigned*>(&t);
}
__device__ __forceinline__ unsigned short f2bf_hw(float f) {
  __hip_bfloat16 h = __float2bfloat16(f);
  return *reinterpret_cast<unsigned short*>(&h);
}

// ---------------------------------------------------------------------------
// k0: one-time weight conversion to frag-major bf16 tables in d_ws.
// ---------------------------------------------------------------------------
__global__ void k0_conv(const float* __restrict__ W0, const float* __restrict__ Wfw,
                        const float* __restrict__ Wbw, unsigned short* __restrict__ wfrag,
                        unsigned short* __restrict__ wlstm) {
  int gid = blockIdx.x * 256 + threadIdx.x;
  if (gid < 4096) {
    int f = gid >> 6, l = gid & 63;
    int k0 = (f >> 2) * 32 + ((l >> 4) << 3);
    int n = (f & 3) * 16 + (l & 15);
    bf16x8 v;
#pragma unroll
    for (int j = 0; j < 8; ++j) v[j] = (short)f2bf_hw(W0[(k0 + j) * 64 + n]);
    *(bf16x8*)(wfrag + gid * 8) = v;
  } else if (gid < 12288) {
    int g2 = gid - 4096;
    const float* W = (g2 < 4096) ? Wfw : Wbw;
    int f = (g2 & 4095) >> 6, l = g2 & 63;
    int wv = f >> 4, gate = (f >> 2) & 3, kf = f & 3;
    int col = gate * 64 + wv * 16 + (l & 15);
    int kr = kf * 32 + ((l >> 4) << 3);
    bf16x8 v;
#pragma unroll
    for (int j = 0; j < 8; ++j) v[j] = (short)f2bf_hw(W[(kr + j) * 256 + col]);
    *(bf16x8*)(wlstm + g2 * 8) = v;
  }
}

// ---------------------------------------------------------------------------
// K1: x = relu(layernorm(obs @ W0 + b0)) -> bf16 [131072, 64]
// 2048 blocks x 256 thr, 48 KB LDS (3 x 16KB ring) -> 3 blocks/CU, 12 waves.
// Chunk = 64 rows x 64 floats (256 B/row). Lookahead-2 staging, vmcnt
// constants account for the 8 B-frag loads per compute region (in-order
// retirement). LDS unit-XOR swizzle: unit' = unit ^ (row & 15).
// ---------------------------------------------------------------------------
__global__ __launch_bounds__(256, 3) void k_dense_ln(
    const float* __restrict__ obs, const unsigned short* __restrict__ wfrag,
    const float* __restrict__ b0, const float* __restrict__ gam,
    const float* __restrict__ bet, unsigned short* __restrict__ xout) {
  __shared__ __align__(16) char lds[49152];  // 3 x 16 KB
  const int tid = threadIdx.x, w = tid >> 6, l = tid & 63;
  const int g = l >> 4, c = l & 15;
  const long blk64 = (long)blockIdx.x * 64;
  const long rb = blk64 + w * 16;

  float b0v[4], gv[4], bv[4];
#pragma unroll
  for (int nt = 0; nt < 4; ++nt) {
    int col = nt * 16 + c;
    b0v[nt] = b0[col]; gv[nt] = gam[col]; bv[nt] = bet[col];
  }
  const unsigned short* wfl = wfrag + l * 8;
  const char* gB = (const char*)obs + blk64 * 2048;

  // staging: instr i -> row = i*16 + w*4 + g, unit' = c holds global unit
  // c ^ (w*4+g); lds off = row*256 + c*16 (linear in tid).
  const int rlo = w * 4 + g;  // row & 15 for this thread's staged rows
  asm volatile("s_waitcnt vmcnt(0)" ::: "memory");

#define K1_STAGE(q)                                                           \
  {                                                                           \
    _Pragma("unroll") for (int i = 0; i < 4; ++i) {                           \
      int row_ = i * 16 + rlo;                                                \
      const char* gp_ = gB + (long)row_ * 2048 + (q) * 256 +                  \
                        (long)((c ^ rlo) * 16);                               \
      char* lp_ = lds + ((q) % 3) * 16384 + (i * 4096 + (w * 64 + l) * 16);   \
      GLDS16(gp_, lp_);                                                       \
    }                                                                         \
  }

  K1_STAGE(0);
  K1_STAGE(1);
  K1_STAGE(2);

  f32x4 acc[4];
#pragma unroll
  for (int nt = 0; nt < 4; ++nt) acc[nt] = (f32x4){0.f, 0.f, 0.f, 0.f};

  // vmcnt before compute(q): instrs issued after stage(q)'s 4 loads
  // (stage=4, B-loads=8/region, in-order retirement)
#pragma unroll
  for (int q = 0; q < 8; ++q) {
    constexpr int VW[8] = {8, 16, 24, 24, 24, 24, 20, 16};
    asm volatile("s_waitcnt vmcnt(%0)" :: "i"(VW[q]) : "memory");
    __builtin_amdgcn_s_barrier();
    __builtin_amdgcn_sched_barrier(0);

    // wave w's A-row m=c -> block row w*16+c; row&15 = c
    const char* rowb = lds + (q % 3) * 16384 + (w * 16 + c) * 256;
#pragma unroll
    for (int kf = 0; kf < 2; ++kf) {
      int fb = (q * 2 + kf) * 4;
      bf16x8 B0 = *(const bf16x8*)(wfl + (fb + 0) * 512);
      bf16x8 B1 = *(const bf16x8*)(wfl + (fb + 1) * 512);
      bf16x8 B2 = *(const bf16x8*)(wfl + (fb + 2) * 512);
      bf16x8 B3 = *(const bf16x8*)(wfl + (fb + 3) * 512);
      int u0 = kf * 8 + g * 2;
      float4 f0 = *(const float4*)(rowb + ((u0 + 0) ^ c) * 16);
      float4 f1 = *(const float4*)(rowb + ((u0 + 1) ^ c) * 16);
      union { bf16x8 v; unsigned u[4]; } af;
      af.u[0] = pk2(f0.x, f0.y); af.u[1] = pk2(f0.z, f0.w);
      af.u[2] = pk2(f1.x, f1.y); af.u[3] = pk2(f1.z, f1.w);
      acc[0] = MFMA_BF16(af.v, B0, acc[0], 0, 0, 0);
      acc[1] = MFMA_BF16(af.v, B1, acc[1], 0, 0, 0);
      acc[2] = MFMA_BF16(af.v, B2, acc[2], 0, 0, 0);
      acc[3] = MFMA_BF16(af.v, B3, acc[3], 0, 0, 0);
    }
    if (q < 5) {  // ring slot (q+3)%3 == q%3: must wait for all readers
      __builtin_amdgcn_s_barrier();
      __builtin_amdgcn_sched_barrier(0);
      K1_STAGE(q + 3);
    }
  }

  // LN epilogue (D: row = 4*g + r within wave tile, col = nt*16 + c)
  float vv[4][4], s1[4], s2[4];
#pragma unroll
  for (int r = 0; r < 4; ++r) { s1[r] = 0.f; s2[r] = 0.f; }
#pragma unroll
  for (int nt = 0; nt < 4; ++nt)
#pragma unroll
    for (int r = 0; r < 4; ++r) {
      float val = acc[nt][r] + b0v[nt];
      vv[nt][r] = val; s1[r] += val; s2[r] += val * val;
    }
#pragma unroll
  for (int r = 0; r < 4; ++r) {
#pragma unroll
    for (int m = 1; m <= 8; m <<= 1) {
      s1[r] += __shfl_xor(s1[r], m);
      s2[r] += __shfl_xor(s2[r], m);
    }
  }
  // per-wave transpose in buf0 region (last read at q=6; all waves past q7's
  // top barrier before any epilogue write)
  unsigned short* xw = (unsigned short*)lds + w * 1024;
#pragma unroll
  for (int r = 0; r < 4; ++r) {
    float mu = s1[r] * 0.015625f;
    float var = s2[r] * 0.015625f - mu * mu;
    float inv = rsqrtf(var + 1e-12f);
    int row = g * 4 + r;
#pragma unroll
    for (int nt = 0; nt < 4; ++nt) {
      float xn = (vv[nt][r] - mu) * inv * gv[nt] + bv[nt];
      xw[(row * 64 + nt * 16 + c) ^ (g << 3)] = f2bf_hw(fmaxf(xn, 0.f));
    }
  }
#pragma unroll
  for (int m2 = 0; m2 < 2; ++m2) {
    int m = m2 * 64 + l;
    int row = m >> 3, u8 = m & 7;
    bf16x8 v = *(const bf16x8*)(xw + ((row * 64 + u8 * 8) ^ ((row >> 2) << 3)));
    *(bf16x8*)(xout + (rb + row) * 64 + u8 * 8) = v;
  }
}

// ---------------------------------------------------------------------------
// K2: bidirectional LSTM + fused projection. 512 blocks x 256 thr.
// R6 skeleton + (1) rcp-merged gate math (7 trans/cell vs 10),
// (2) x-part MFMAs pipelined one step ahead (off the h-serial chain):
//     owner vmcnt shifted to slot t+2 so slot t+1 is readable during step t.
// ---------------------------------------------------------------------------
__global__ __launch_bounds__(256, 2) void k_lstm(
    const unsigned short* __restrict__ x, const unsigned short* __restrict__ wlstm,
    const float* __restrict__ bfw, const float* __restrict__ bbw,
    const float* __restrict__ Wc, const float* __restrict__ bc,
    float* __restrict__ out) {
  __shared__ __align__(16) char xl[65536];
  __shared__ unsigned short hl[2 * 1024];
  const int tid = threadIdx.x, w = tid >> 6, l = tid & 63;
  const int g = l >> 4, c = l & 15;
  const int dir = blockIdx.x >> 8;
  const int sq = (blockIdx.x & 255) * 16;
  const float* bias = dir ? bbw : bfw;

  bf16x8 Bf[4][4];
  const unsigned short* wl = wlstm + ((long)dir * 4096 + w * 16 * 64) * 8;
#pragma unroll
  for (int gate = 0; gate < 4; ++gate)
#pragma unroll
    for (int kf = 0; kf < 4; ++kf)
      Bf[gate][kf] = *(const bf16x8*)(wl + ((gate * 4 + kf) * 64 + l) * 8);
  float bz[4];
#pragma unroll
  for (int gate = 0; gate < 4; ++gate) bz[gate] = bias[gate * 64 + w * 16 + c];

  bf16x8 Pc[2];
#pragma unroll
  for (int kf = 0; kf < 2; ++kf)
#pragma unroll
    for (int j = 0; j < 8; ++j) Pc[kf][j] = 0;
  float bcv = 0.f;
  if (w == 0 && c < 8) {
#pragma unroll
    for (int kf = 0; kf < 2; ++kf)
#pragma unroll
      for (int j = 0; j < 8; ++j)
        Pc[kf][j] = (short)f2bf_hw(Wc[(kf * 32 + g * 8 + j) * 8 + c]);
    bcv = bc[c];
  }

  asm volatile("s_waitcnt vmcnt(0)" ::: "memory");

  // stage: wave w issues slots tt = w*8+j (consumption order), 1 glds/slot
  const int ss = l >> 3, sc = l & 7;
#pragma unroll
  for (int j = 0; j < 8; ++j) {
    int tt = w * 8 + j;
    int te = dir ? 31 - tt : tt;
#pragma unroll
    for (int p = 0; p < 2; ++p) {
      int s = p * 8 + ss;
      const char* gp = (const char*)x +
          ((long)(sq + s) * 32 + te) * 128 + (long)(sc ^ (s & 7)) * 16;
      char* lp = xl + tt * 2048 + p * 1024;
      GLDS16(gp, lp);
    }
  }

  for (int i = tid; i < 1024; i += 256) ((unsigned*)hl)[i] = 0u;
  float cs[4] = {0.f, 0.f, 0.f, 0.f};

  // prologue: slots 0 AND 1 must be resident (step 0 reads Ax(0) and Ax(1))
  if (w == 0) asm volatile("s_waitcnt vmcnt(12)" ::: "memory");
  asm volatile("s_waitcnt lgkmcnt(0)" ::: "memory");
  __builtin_amdgcn_s_barrier();
  __builtin_amdgcn_sched_barrier(0);

  const int hq = w >> 1;
  const int hgp = ((w & 1) * 2 + (c >> 3)) * 16;
  const int hlo = c & 7;

  // accx(0): x-part pre-activations for step 0
  f32x4 accx[4];
  {
    const char* xt = xl + 0 * 2048 + c * 128;
    bf16x8 Ax0 = *(const bf16x8*)(xt + (long)((g) ^ (c & 7)) * 16);
    bf16x8 Ax1 = *(const bf16x8*)(xt + (long)((4 + g) ^ (c & 7)) * 16);
#pragma unroll
    for (int gate = 0; gate < 4; ++gate) {
      f32x4 b = (f32x4){bz[gate], bz[gate], bz[gate], bz[gate]};
      accx[gate] = MFMA_BF16(Ax1, Bf[gate][1],
                             MFMA_BF16(Ax0, Bf[gate][0], b, 0, 0, 0), 0, 0, 0);
    }
  }

  int p = 0;
#pragma unroll
  for (int t = 0; t < 32; ++t) {
    bf16x8 Ah0 = *(const bf16x8*)((const char*)hl + p * 2048 + l * 16);
    bf16x8 Ah1 = *(const bf16x8*)((const char*)hl + p * 2048 + 1024 + l * 16);

    f32x4 acc[4];
#pragma unroll
    for (int gate = 0; gate < 4; ++gate)
      acc[gate] = MFMA_BF16(Ah1, Bf[gate][3],
                            MFMA_BF16(Ah0, Bf[gate][2], accx[gate], 0, 0, 0),
                            0, 0, 0);

    // accx(t+1): independent of h -> overlaps the elementwise below
    if (t + 1 < 32) {
      const char* xt = xl + (t + 1) * 2048 + c * 128;
      bf16x8 Ax0 = *(const bf16x8*)(xt + (long)((g) ^ (c & 7)) * 16);
      bf16x8 Ax1 = *(const bf16x8*)(xt + (long)((4 + g) ^ (c & 7)) * 16);
#pragma unroll
      for (int gate = 0; gate < 4; ++gate) {
        f32x4 b = (f32x4){bz[gate], bz[gate], bz[gate], bz[gate]};
        accx[gate] = MFMA_BF16(Ax1, Bf[gate][1],
                               MFMA_BF16(Ax0, Bf[gate][0], b, 0, 0, 0), 0, 0, 0);
      }
    }

    // rcp-merged gates: 5 exp + 2 rcp per cell (safe: |z| << 44, |c| <= 32)
    const int wb = (p ^ 1) * 1024;
#pragma unroll
    for (int r = 0; r < 4; ++r) {
      float ei = __expf(-acc[0][r]);
      float ej = __expf(2.f * acc[1][r]);
      float ef = __expf(-(acc[2][r] + 1.f));
      float eo = __expf(-acc[3][r]);
      float p12 = (1.f + ei) * (1.f + ej);
      float r3 = __builtin_amdgcn_rcpf(p12 * (1.f + ef));
      float it = (ej - 1.f) * (1.f + ef) * r3;   // sigm(i)*tanh(j)
      float sf = p12 * r3;                       // sigm(f+1)
      cs[r] = cs[r] * sf + it;
      float ec = __expf(2.f * cs[r]);
      float r2 = __builtin_amdgcn_rcpf((1.f + eo) * (1.f + ec));
      hl[wb + (hq * 64 + hgp + 4 * g + r) * 8 + hlo] =
          f2bf_hw((ec - 1.f) * r2);              // tanh(c)*sigm(o)
    }

    // owner guarantees slot t+2 before next step (t+1 reads Ax(t+2))
    if (t + 2 < 32) {
      if (w == ((t + 2) >> 3))
        asm volatile("s_waitcnt vmcnt(%0)" :: "i"(14 - 2 * ((t + 2) & 7)) : "memory");
    }
    asm volatile("s_waitcnt lgkmcnt(0)" ::: "memory");
    __builtin_amdgcn_s_barrier();
    __builtin_amdgcn_sched_barrier(0);

    if (w == 0 && t >= 1) {
      int te = dir ? 31 - t : t;
      f32x4 pa = (f32x4){0.f, 0.f, 0.f, 0.f};
      pa = MFMA_BF16(Ah0, Pc[0], pa, 0, 0, 0);
      pa = MFMA_BF16(Ah1, Pc[1], pa, 0, 0, 0);
      if (c < 8) {
        int tp = dir ? 32 - t : t - 1;
#pragma unroll
        for (int r = 0; r < 4; ++r) {
          long orow = (long)dir * 4096 + sq + 4 * g + r;
          out[(orow * 32 + tp) * 8 + c] = tanhf(pa[r] + bcv);
        }
      }
    }
    p ^= 1;
  }

  if (w == 0) {
    bf16x8 Ph0 = *(const bf16x8*)((const char*)hl + p * 2048 + l * 16);
    bf16x8 Ph1 = *(const bf16x8*)((const char*)hl + p * 2048 + 1024 + l * 16);
    f32x4 pa = (f32x4){0.f, 0.f, 0.f, 0.f};
    pa = MFMA_BF16(Ph0, Pc[0], pa, 0, 0, 0);
    pa = MFMA_BF16(Ph1, Pc[1], pa, 0, 0, 0);
    if (c < 8) {
      int tp = dir ? 0 : 31;
#pragma unroll
      for (int r = 0; r < 4; ++r) {
        long orow = (long)dir * 4096 + sq + 4 * g + r;
        out[(orow * 32 + tp) * 8 + c] = tanhf(pa[r] + bcv);
      }
    }
  }
}

extern "C" void kernel_launch(void* const* d_in, const int* in_sizes, int n_in,
                              void* d_out, int out_size, void* d_ws, size_t ws_size,
                              hipStream_t stream) {
  const float* obs = (const float*)d_in[0];
  const float* W0  = (const float*)d_in[1];
  const float* b0  = (const float*)d_in[2];
  const float* gam = (const float*)d_in[3];
  const float* bet = (const float*)d_in[4];
  const float* Wfw = (const float*)d_in[5];
  const float* bfw = (const float*)d_in[6];
  const float* Wbw = (const float*)d_in[7];
  const float* bbw = (const float*)d_in[8];
  const float* Wc  = (const float*)d_in[9];
  const float* bc  = (const float*)d_in[10];
  float* out = (float*)d_out;

  unsigned short* wfrag = (unsigned short*)d_ws;       // 64 KB
  unsigned short* wlstm = wfrag + 4096 * 8;            // 128 KB
  unsigned short* xbf   = wlstm + 8192 * 8;            // 16.78 MB

  k0_conv<<<48, 256, 0, stream>>>(W0, Wfw, Wbw, wfrag, wlstm);
  k_dense_ln<<<2048, 256, 0, stream>>>(obs, wfrag, b0, gam, bet, xbf);
  k_lstm<<<512, 256, 0, stream>>>(xbf, wlstm, bfw, bbw, Wc, bc, out);
}